// Round 8
// baseline (13584.135 us; speedup 1.0000x reference)
//
#include <hip/hip_runtime.h>
#include <cstdint>
#include <cstddef>

#define NB 256   // batch
#define NT 512   // time steps
#define ND 64    // input dim
#define NH 512   // hidden dim
#define KT_TOT 18  // 16 h-ktiles + 2 x-ktiles (K = 512 + 64)

typedef __attribute__((ext_vector_type(8))) short short8;
typedef __attribute__((ext_vector_type(4))) float f32x4;

__device__ __forceinline__ unsigned short f2bf(float f) {
  union { float f; uint32_t u; } v; v.f = f;
  uint32_t u = v.u;
  return (unsigned short)((u + 0x7FFFu + ((u >> 16) & 1u)) >> 16);  // RNE
}
__device__ __forceinline__ float bf2f(unsigned short b) {
  union { uint32_t u; float f; } v; v.u = ((uint32_t)b) << 16;
  return v.f;
}
__device__ __forceinline__ void split8(const float* v, short8& hi, short8& lo) {
#pragma unroll
  for (int e = 0; e < 8; ++e) {
    unsigned short hb = f2bf(v[e]);
    hi[e] = (short)hb;
    lo[e] = (short)f2bf(v[e] - bf2f(hb));
  }
}
__device__ __forceinline__ float tanh_fast(float x) {
  float ax = fabsf(x);
  float e  = __expf(-2.0f * ax);
  float t  = (1.0f - e) * __frcp_rn(1.0f + e);
  return copysignf(t, x);
}

// Pack split-bf16 W into fragment-major stream layout:
//   wp[(((kt*8 + w)*4 + nt)*2 + p)*64 + lane][8]
// value = plane p of split(W[n][k]), n = w*64 + nt*16 + (lane&15),
//         k = kt*32 + (lane>>4)*8 + e;  kt<16 -> W_hh, kt>=16 -> W_ih.
__global__ void prep_kernel(const float* __restrict__ whh,
                            const float* __restrict__ wih,
                            unsigned short* __restrict__ wp) {
  const int id = blockIdx.x * 256 + threadIdx.x;   // 0 .. 73727
  if (id >= KT_TOT * 8 * 4 * 2 * 64) return;
  const int lane = id & 63;
  const int p    = (id >> 6) & 1;
  const int nt   = (id >> 7) & 3;
  const int w    = (id >> 9) & 7;
  const int kt   = id >> 12;
  const int n    = w * 64 + nt * 16 + (lane & 15);
  const int kb   = kt * 32 + (lane >> 4) * 8;
  short8 o;
#pragma unroll
  for (int e = 0; e < 8; ++e) {
    const int k = kb + e;
    const float v = (kt < 16) ? whh[(size_t)n * NH + k]
                              : wih[(size_t)n * ND + (k - NH)];
    const unsigned short hb = f2bf(v);
    o[e] = (short)((p == 0) ? hb : f2bf(v - bf2f(hb)));
  }
  *(short8*)(wp + (size_t)id * 8) = o;
}

// Batch-parallel persistent RNN: 16 blocks x 8 waves. Block owns 16 batch
// rows and computes ALL 512 hidden cols each step (wave w: cols w*64..+63).
// h lives in block-local LDS (hi+lo planes) -- the only sync is
// __syncthreads. W is streamed from L2 every step (packed layout, 3-deep
// register prefetch ring). No cross-block communication at all.
__global__ __launch_bounds__(512, 2) void rnn_persist(
    const float* __restrict__ x, const unsigned short* __restrict__ wp,
    const float* __restrict__ bih, const float* __restrict__ bhh,
    const float* __restrict__ who, const float* __restrict__ bho,
    float* __restrict__ out)
{
  __shared__ unsigned short hst[2][16][520];   // hi/lo planes, padded rows
  __shared__ float posum[8][16];

  const int bg   = blockIdx.x;        // 0..15 batch group
  const int w    = threadIdx.x >> 6;  // wave 0..7 -> cols w*64..w*64+63
  const int lane = threadIdx.x & 63;
  const int lm   = lane & 15;
  const int lg   = lane >> 4;
  const int lkb  = lg * 8;
  const int bm   = bg * 16;

  // per-nt bias / out-weight
  float bv[4], wov[4];
#pragma unroll
  for (int nt = 0; nt < 4; ++nt) {
    const int n = w * 64 + nt * 16 + lm;
    bv[nt]  = bih[n] + bhh[n];
    wov[nt] = who[n];
  }
  const float bo = bho[0];

  // h(-1) = 0
  {
    unsigned* hz = (unsigned*)&hst[0][0][0];
    const int nw = 2 * 16 * 520 / 2;
    for (int i = threadIdx.x; i < nw; i += 512) hz[i] = 0u;
  }
  __syncthreads();

  // x A-frag row pointer (rows shared across waves; L1-cached)
  const float* xrow = x + (size_t)(bm + lm) * NT * ND + lkb;
  f32x4 xr[4];
#pragma unroll
  for (int xt = 0; xt < 2; ++xt) {
    xr[2 * xt]     = *(const f32x4*)(xrow + xt * 32);
    xr[2 * xt + 1] = *(const f32x4*)(xrow + xt * 32 + 4);
  }

  // this wave's W stream base; per kt: 4 nt x 2 p x 1KB frags
  const unsigned short* wbase = wp + (size_t)w * 4096;

  for (int t = 0; t < NT; ++t) {
    // x(t) split A-frags
    short8 ax_hi[2], ax_lo[2];
#pragma unroll
    for (int xt = 0; xt < 2; ++xt) {
      float v[8];
      *(f32x4*)&v[0] = xr[2 * xt];
      *(f32x4*)&v[4] = xr[2 * xt + 1];
      split8(v, ax_hi[xt], ax_lo[xt]);
    }

    f32x4 acc[4][3];
#pragma unroll
    for (int nt = 0; nt < 4; ++nt)
#pragma unroll
      for (int s = 0; s < 3; ++s) acc[nt][s] = (f32x4){0.f, 0.f, 0.f, 0.f};

    // 3-deep W prefetch ring
    short8 wb[3][4][2];
#pragma unroll
    for (int s = 0; s < 3; ++s)
#pragma unroll
      for (int nt = 0; nt < 4; ++nt)
#pragma unroll
        for (int p = 0; p < 2; ++p)
          wb[s][nt][p] = *(const short8*)(wbase + (size_t)s * 32768 +
                                          (nt * 2 + p) * 512 + lane * 8);

    // K loop: 16 h-ktiles (A from LDS) + 2 x-ktiles (A in regs)
#pragma unroll
    for (int kt = 0; kt < KT_TOT; ++kt) {
      const int s = kt % 3;
      short8 ah, al;
      if (kt < 16) {
        ah = *(const short8*)&hst[0][lm][kt * 32 + lkb];
        al = *(const short8*)&hst[1][lm][kt * 32 + lkb];
      } else {
        ah = ax_hi[kt - 16];
        al = ax_lo[kt - 16];
      }
#pragma unroll
      for (int nt = 0; nt < 4; ++nt) {
        acc[nt][0] = __builtin_amdgcn_mfma_f32_16x16x32_bf16(ah, wb[s][nt][0], acc[nt][0], 0, 0, 0);
        acc[nt][1] = __builtin_amdgcn_mfma_f32_16x16x32_bf16(ah, wb[s][nt][1], acc[nt][1], 0, 0, 0);
        acc[nt][2] = __builtin_amdgcn_mfma_f32_16x16x32_bf16(al, wb[s][nt][0], acc[nt][2], 0, 0, 0);
      }
      if (kt + 3 < KT_TOT) {
#pragma unroll
        for (int nt = 0; nt < 4; ++nt)
#pragma unroll
          for (int p = 0; p < 2; ++p)
            wb[s][nt][p] = *(const short8*)(wbase + (size_t)(kt + 3) * 32768 +
                                            (nt * 2 + p) * 512 + lane * 8);
      }
    }

    // x(t+1) prefetch (lands during epilogue/barriers)
    if (t + 1 < NT) {
#pragma unroll
      for (int xt = 0; xt < 2; ++xt) {
        xr[2 * xt]     = *(const f32x4*)(xrow + (size_t)(t + 1) * ND + xt * 32);
        xr[2 * xt + 1] = *(const f32x4*)(xrow + (size_t)(t + 1) * ND + xt * 32 + 4);
      }
    }

    __syncthreads();   // A: all hst reads of h(t-1) complete

    // epilogue: tanh, split, write h(t) to LDS, out partials
    float po[4] = {0.f, 0.f, 0.f, 0.f};
#pragma unroll
    for (int nt = 0; nt < 4; ++nt) {
#pragma unroll
      for (int r = 0; r < 4; ++r) {
        float pre = acc[nt][0][r] + acc[nt][1][r] + acc[nt][2][r] + bv[nt];
        float hv  = tanh_fast(pre);
        const int m   = lg * 4 + r;
        const int col = w * 64 + nt * 16 + lm;
        const unsigned short hb = f2bf(hv);
        hst[0][m][col] = hb;
        hst[1][m][col] = f2bf(hv - bf2f(hb));
        po[r] += hv * wov[nt];
      }
    }
#pragma unroll
    for (int s2 = 1; s2 < 16; s2 <<= 1)
#pragma unroll
      for (int r = 0; r < 4; ++r) po[r] += __shfl_xor(po[r], s2, 64);
    if (lm == 0) {
#pragma unroll
      for (int r = 0; r < 4; ++r) posum[w][lg * 4 + r] = po[r];
    }

    __syncthreads();   // B: h(t) + posum visible to all waves

    if (w == 0 && lane < 16) {
      float s8 = 0.f;
#pragma unroll
      for (int ww = 0; ww < 8; ++ww) s8 += posum[ww][lane];
      out[(size_t)(bm + lane) * NT + t] = s8 + bo;
    }
  }
}

extern "C" void kernel_launch(void* const* d_in, const int* in_sizes, int n_in,
                              void* d_out, int out_size, void* d_ws, size_t ws_size,
                              hipStream_t stream) {
  const float* x   = (const float*)d_in[0];
  const float* wih = (const float*)d_in[1];
  const float* whh = (const float*)d_in[2];
  const float* bih = (const float*)d_in[3];
  const float* bhh = (const float*)d_in[4];
  const float* who = (const float*)d_in[5];
  const float* bho = (const float*)d_in[6];
  float* out = (float*)d_out;

  // ws: packed W stream (18*8*4*2*64*8 u16 = 1.125 MB)
  unsigned short* wp = (unsigned short*)d_ws;

  prep_kernel<<<288, 256, 0, stream>>>(whh, wih, wp);
  rnn_persist<<<16, 512, 0, stream>>>(x, wp, bih, bhh, who, bho, out);
}

// Round 9
// 13427.238 us; speedup vs baseline: 1.0117x; 1.0117x over previous
//
#include <hip/hip_runtime.h>
#include <cstdint>
#include <cstddef>

#define NB 256   // batch
#define NT 512   // time steps
#define ND 64    // input dim
#define NH 512   // hidden dim
#define KT_TOT 18  // 16 h-ktiles + 2 x-ktiles (K = 512 + 64)

typedef __attribute__((ext_vector_type(8))) short short8;
typedef __attribute__((ext_vector_type(4))) float f32x4;

__device__ __forceinline__ unsigned short f2bf(float f) {
  union { float f; uint32_t u; } v; v.f = f;
  uint32_t u = v.u;
  return (unsigned short)((u + 0x7FFFu + ((u >> 16) & 1u)) >> 16);  // RNE
}
__device__ __forceinline__ float bf2f(unsigned short b) {
  union { uint32_t u; float f; } v; v.u = ((uint32_t)b) << 16;
  return v.f;
}
__device__ __forceinline__ void split8(const float* v, short8& hi, short8& lo) {
#pragma unroll
  for (int e = 0; e < 8; ++e) {
    unsigned short hb = f2bf(v[e]);
    hi[e] = (short)hb;
    lo[e] = (short)f2bf(v[e] - bf2f(hb));
  }
}
__device__ __forceinline__ float tanh_fast(float x) {
  float ax = fabsf(x);
  float e  = __expf(-2.0f * ax);
  float t  = (1.0f - e) * __frcp_rn(1.0f + e);
  return copysignf(t, x);
}

// Pack split-bf16 W into fragment-major stream layout:
//   offset = ((kt*8 + w)*8 + nt*2 + p)*512 + lane*8
// value = plane p of split(W[n][k]), n = w*64 + nt*16 + (lane&15),
//         k = kt*32 + (lane>>4)*8 + e;  kt<16 -> W_hh, kt>=16 -> W_ih.
__global__ void prep_kernel(const float* __restrict__ whh,
                            const float* __restrict__ wih,
                            unsigned short* __restrict__ wp) {
  const int id = blockIdx.x * 256 + threadIdx.x;   // 0 .. 73727
  if (id >= KT_TOT * 8 * 4 * 2 * 64) return;
  const int lane = id & 63;
  const int p    = (id >> 6) & 1;
  const int nt   = (id >> 7) & 3;
  const int w    = (id >> 9) & 7;
  const int kt   = id >> 12;
  const int n    = w * 64 + nt * 16 + (lane & 15);
  const int kb   = kt * 32 + (lane >> 4) * 8;
  short8 o;
#pragma unroll
  for (int e = 0; e < 8; ++e) {
    const int k = kb + e;
    const float v = (kt < 16) ? whh[(size_t)n * NH + k]
                              : wih[(size_t)n * ND + (k - NH)];
    const unsigned short hb = f2bf(v);
    o[e] = (short)((p == 0) ? hb : f2bf(v - bf2f(hb)));
  }
  *(short8*)(wp + (size_t)id * 8) = o;
}

// Batch-parallel persistent RNN: 16 blocks x 8 waves. Block = 16 batch rows,
// computes ALL 512 hidden cols each step (wave w: cols w*64..w*64+63).
// h double-buffered in block-local LDS -> ONE __syncthreads per step.
// W streamed from L2 each step through a 2-deep STATICALLY-INDEXED register
// ring (named wA/wB buffers, macro-expanded literal kt -- rule #20 fix).
__global__ __launch_bounds__(512, 2) void rnn_batch(
    const float* __restrict__ x, const unsigned short* __restrict__ wp,
    const float* __restrict__ bih, const float* __restrict__ bhh,
    const float* __restrict__ who, const float* __restrict__ bho,
    float* __restrict__ out)
{
  __shared__ unsigned short hstbuf[2][2][16][520];   // [time][plane][row][col+pad]
  __shared__ float posum[2][8][16];

  const int bg   = blockIdx.x;        // 0..15 batch group
  const int w    = threadIdx.x >> 6;  // wave 0..7 -> cols w*64..w*64+63
  const int lane = threadIdx.x & 63;
  const int lm   = lane & 15;
  const int lg   = lane >> 4;
  const int lkb  = lg * 8;
  const int bm   = bg * 16;

  float bv[4], wov[4];
#pragma unroll
  for (int nt = 0; nt < 4; ++nt) {
    const int n = w * 64 + nt * 16 + lm;
    bv[nt]  = bih[n] + bhh[n];
    wov[nt] = who[n];
  }
  const float bo = bho[0];

  // h(-1) = 0 in time-buffer 0
  {
    unsigned* hz = (unsigned*)&hstbuf[0][0][0][0];
    const int nw = 2 * 16 * 520 / 2;
    for (int i = threadIdx.x; i < nw; i += 512) hz[i] = 0u;
  }
  __syncthreads();

  const float* xrow = x + (size_t)(bm + lm) * NT * ND + lkb;
  f32x4 xr[4];
#pragma unroll
  for (int xt = 0; xt < 2; ++xt) {
    xr[2 * xt]     = *(const f32x4*)(xrow + xt * 32);
    xr[2 * xt + 1] = *(const f32x4*)(xrow + xt * 32 + 4);
  }

  const unsigned short* wbase = wp + (size_t)w * 4096 + lane * 8;

#define WLOAD(BUF, KT) do {                                              \
    const unsigned short* _wb = wbase + (size_t)(KT) * 32768;            \
    _Pragma("unroll")                                                    \
    for (int _nt = 0; _nt < 4; ++_nt) {                                  \
      BUF[_nt][0] = *(const short8*)(_wb + (_nt * 2 + 0) * 512);         \
      BUF[_nt][1] = *(const short8*)(_wb + (_nt * 2 + 1) * 512);         \
    }                                                                    \
  } while (0)

#define KSTEP(KT, BUF) do {                                              \
    short8 _ah, _al;                                                     \
    if ((KT) < 16) {                                                     \
      _ah = *(const short8*)&hc[0][lm][(KT) * 32 + lkb];                 \
      _al = *(const short8*)&hc[1][lm][(KT) * 32 + lkb];                 \
    } else {                                                             \
      _ah = ax_hi[(KT) & 1];                                             \
      _al = ax_lo[(KT) & 1];                                             \
    }                                                                    \
    _Pragma("unroll")                                                    \
    for (int _nt = 0; _nt < 4; ++_nt) {                                  \
      acc[_nt][0] = __builtin_amdgcn_mfma_f32_16x16x32_bf16(_ah, BUF[_nt][0], acc[_nt][0], 0, 0, 0); \
      acc[_nt][1] = __builtin_amdgcn_mfma_f32_16x16x32_bf16(_ah, BUF[_nt][1], acc[_nt][1], 0, 0, 0); \
      acc[_nt][2] = __builtin_amdgcn_mfma_f32_16x16x32_bf16(_al, BUF[_nt][0], acc[_nt][2], 0, 0, 0); \
    }                                                                    \
    if ((KT) + 2 < KT_TOT) WLOAD(BUF, (KT) + 2);                         \
  } while (0)

  short8 wA[4][2], wB[4][2];
  WLOAD(wA, 0);
  WLOAD(wB, 1);

  for (int t = 0; t < NT; ++t) {
    const int r = t & 1;
    const unsigned short (*hc)[16][520] = hstbuf[r];      // read h(t-1)
    unsigned short (*hw)[16][520] = hstbuf[r ^ 1];        // write h(t)

    // x(t) split A-frags (kt 16 -> index 0, kt 17 -> index 1)
    short8 ax_hi[2], ax_lo[2];
#pragma unroll
    for (int xt = 0; xt < 2; ++xt) {
      float v[8];
      *(f32x4*)&v[0] = xr[2 * xt];
      *(f32x4*)&v[4] = xr[2 * xt + 1];
      split8(v, ax_hi[xt], ax_lo[xt]);
    }

    f32x4 acc[4][3];
#pragma unroll
    for (int nt = 0; nt < 4; ++nt)
#pragma unroll
      for (int s = 0; s < 3; ++s) acc[nt][s] = (f32x4){0.f, 0.f, 0.f, 0.f};

    KSTEP(0, wA);  KSTEP(1, wB);  KSTEP(2, wA);  KSTEP(3, wB);
    KSTEP(4, wA);  KSTEP(5, wB);  KSTEP(6, wA);  KSTEP(7, wB);
    KSTEP(8, wA);  KSTEP(9, wB);  KSTEP(10, wA); KSTEP(11, wB);
    KSTEP(12, wA); KSTEP(13, wB); KSTEP(14, wA); KSTEP(15, wB);
    KSTEP(16, wA); KSTEP(17, wB);

    // refill ring for t+1 and prefetch x(t+1): latency hides under epilogue
    WLOAD(wA, 0);
    WLOAD(wB, 1);
    if (t + 1 < NT) {
#pragma unroll
      for (int xt = 0; xt < 2; ++xt) {
        xr[2 * xt]     = *(const f32x4*)(xrow + (size_t)(t + 1) * ND + xt * 32);
        xr[2 * xt + 1] = *(const f32x4*)(xrow + (size_t)(t + 1) * ND + xt * 32 + 4);
      }
    }

    // epilogue: tanh, split, write h(t) to the OTHER LDS buffer, out partials
    float po[4] = {0.f, 0.f, 0.f, 0.f};
#pragma unroll
    for (int nt = 0; nt < 4; ++nt) {
#pragma unroll
      for (int rr = 0; rr < 4; ++rr) {
        float pre = acc[nt][0][rr] + acc[nt][1][rr] + acc[nt][2][rr] + bv[nt];
        float hv  = tanh_fast(pre);
        const int m   = lg * 4 + rr;
        const int col = w * 64 + nt * 16 + lm;
        const unsigned short hb = f2bf(hv);
        hw[0][m][col] = hb;
        hw[1][m][col] = f2bf(hv - bf2f(hb));
        po[rr] += hv * wov[nt];
      }
    }
#pragma unroll
    for (int s2 = 1; s2 < 16; s2 <<= 1)
#pragma unroll
      for (int rr = 0; rr < 4; ++rr) po[rr] += __shfl_xor(po[rr], s2, 64);
    if (lm == 0) {
#pragma unroll
      for (int rr = 0; rr < 4; ++rr) posum[r][w][lg * 4 + rr] = po[rr];
    }

    __syncthreads();   // h(t) + posum visible; only barrier in the step

    if (w == 0 && lane < 16) {
      float s8 = 0.f;
#pragma unroll
      for (int ww = 0; ww < 8; ++ww) s8 += posum[r][ww][lane];
      out[(size_t)(bm + lane) * NT + t] = s8 + bo;
    }
  }
#undef KSTEP
#undef WLOAD
}

extern "C" void kernel_launch(void* const* d_in, const int* in_sizes, int n_in,
                              void* d_out, int out_size, void* d_ws, size_t ws_size,
                              hipStream_t stream) {
  const float* x   = (const float*)d_in[0];
  const float* wih = (const float*)d_in[1];
  const float* whh = (const float*)d_in[2];
  const float* bih = (const float*)d_in[3];
  const float* bhh = (const float*)d_in[4];
  const float* who = (const float*)d_in[5];
  const float* bho = (const float*)d_in[6];
  float* out = (float*)d_out;

  // ws: packed W stream (18*8*4*2*64*8 u16 = 1.125 MB)
  unsigned short* wp = (unsigned short*)d_ws;

  prep_kernel<<<288, 256, 0, stream>>>(whh, wih, wp);
  rnn_batch<<<16, 512, 0, stream>>>(x, wp, bih, bhh, who, bho, out);
}

// Round 10
// 1889.968 us; speedup vs baseline: 7.1875x; 7.1045x over previous
//
#include <hip/hip_runtime.h>
#include <cstdint>
#include <cstddef>

#define NB 256   // batch
#define NT 512   // time steps
#define ND 64    // input dim
#define NH 512   // hidden dim

typedef __attribute__((ext_vector_type(8))) _Float16 half8;
typedef __attribute__((ext_vector_type(4))) float f32x4;
typedef unsigned long long ull;

union H8 { half8 h; ull q[2]; };

__device__ __forceinline__ float tanh_fast(float x) {
  float ax = fabsf(x);
  float e  = __expf(-2.0f * ax);
  float t  = (1.0f - e) * __frcp_rn(1.0f + e);
  return copysignf(t, x);
}

// Pack W (W_hh | W_ih) to fp16 fragment-major:
//   unit u = ((kt*4 + cb)*8 + j)*64 + lane, 8 halves each.
//   n = cb*128 + j*16 + (lane&15); k = kt*32 + (lane>>4)*8 + e.
//   kt<16 -> W_hh[n][k], kt>=16 -> W_ih[n][k-512].
__global__ void prep_kernel(const float* __restrict__ whh,
                            const float* __restrict__ wih,
                            _Float16* __restrict__ wpk) {
  const int id = blockIdx.x * 256 + threadIdx.x;   // 0..36863
  if (id >= 18 * 4 * 8 * 64) return;
  const int lane = id & 63;
  const int j    = (id >> 6) & 7;
  const int cbv  = (id >> 9) & 3;
  const int kt   = id >> 11;
  const int n    = cbv * 128 + j * 16 + (lane & 15);
  const int kb   = kt * 32 + (lane >> 4) * 8;
  half8 o;
#pragma unroll
  for (int e = 0; e < 8; ++e) {
    const int k = kb + e;
    const float v = (kt < 16) ? whh[(size_t)n * NH + k]
                              : wih[(size_t)n * ND + (k - NH)];
    o[e] = (_Float16)v;   // RNE
  }
  *(half8*)(wpk + (size_t)id * 8) = o;
}

__global__ void init_kernel(unsigned int* __restrict__ flags) {
  int i = blockIdx.x * 256 + threadIdx.x;
  if (i < 2048) flags[i] = 0u;
}

// out[b][t] = b_ho + sum_cb partial[cb][b][t]
__global__ void combine_kernel(const float* __restrict__ partial,
                               const float* __restrict__ bho,
                               float* __restrict__ out) {
  int id = blockIdx.x * 256 + threadIdx.x;   // 131072
  out[id] = bho[0] + partial[id] + partial[id + NB * NT]
          + partial[id + 2 * NB * NT] + partial[id + 3 * NB * NT];
}

// Column-split persistent RNN, fp16: 64 blocks (16 bg x 4 cb) x 4 waves.
// Block = 16 batch rows x 128 cols; wave = 32 cols. W fp16 single-plane,
// STATIONARY: kt 0..7 in LDS, kt 8..15 + x-tiles in VGPRs. h fp16 hi+lo
// split, both terms accumulate into ONE acc. Exchange via relaxed
// agent-scope atomics (proven R4/R6/R7); per-block flag; wave-role split:
// wave0 does flag+out while waves1-3 spin+fetch one peer block each.
__global__ __launch_bounds__(256, 1) void rnn_f16(
    const float* __restrict__ x, const _Float16* __restrict__ wpk,
    const float* __restrict__ bih, const float* __restrict__ bhh,
    const float* __restrict__ who,
    _Float16* __restrict__ hglob,    // [2][16 bg][16 gk][2 p][512] halves
    unsigned int* __restrict__ flags,// [16 bg][4 cb] u32, 128B apart
    float* __restrict__ partial)     // [4 cb][NB][NT] f32
{
  __shared__ _Float16 wlds[8][8][64][8];      // 64 KiB: W_hh kt 0..7
  __shared__ _Float16 hpeer[2][2][16][520];   // 65 KiB: [buf][plane][row][col]
  __shared__ _Float16 tstage[4][2][16][40];   // 10 KiB
  __shared__ float posum[4][16];

  const int bid  = blockIdx.x;
  const int bg   = bid >> 2;
  const int cb   = bid & 3;
  const int w    = threadIdx.x >> 6;
  const int lane = threadIdx.x & 63;
  const int lm   = lane & 15;
  const int lg   = lane >> 4;
  const int lkb  = lg * 8;
  const int bm   = bg * 16;
  const int n0   = cb * 128 + w * 32;
  const int gko  = cb * 4 + w;                // chunk this wave publishes

  // ---- W_hh kt 0..7 -> LDS (fragment-major copy) ----
  for (int i = threadIdx.x; i < 8 * 8 * 64; i += 256) {
    const int kt = i >> 9, jj = (i >> 6) & 7, ln = i & 63;
    const _Float16* src = wpk + (size_t)(((kt * 4 + cb) * 8 + jj) * 64 + ln) * 8;
    *(half8*)&wlds[kt][jj][ln][0] = *(const half8*)src;
  }
  // ---- W_hh kt 8..15 + W_ih kt 16,17 -> VGPRs ----
  half8 wreg[8][2], wx[2][2];
#pragma unroll
  for (int q = 0; q < 8; ++q)
#pragma unroll
    for (int nt = 0; nt < 2; ++nt)
      wreg[q][nt] = *(const half8*)(wpk +
        (size_t)((((q + 8) * 4 + cb) * 8 + (w * 2 + nt)) * 64 + lane) * 8);
#pragma unroll
  for (int q = 0; q < 2; ++q)
#pragma unroll
    for (int nt = 0; nt < 2; ++nt)
      wx[q][nt] = *(const half8*)(wpk +
        (size_t)((((q + 16) * 4 + cb) * 8 + (w * 2 + nt)) * 64 + lane) * 8);

  float bv[2], wov[2];
#pragma unroll
  for (int nt = 0; nt < 2; ++nt) {
    const int n = n0 + nt * 16 + lm;
    bv[nt]  = bih[n] + bhh[n];
    wov[nt] = who[n];
  }

  // h(-1) = 0 in hpeer buffer 0
  for (int i = threadIdx.x; i < 2 * 16 * 520 * 2 / 4; i += 256)
    ((unsigned*)&hpeer[0][0][0][0])[i] = 0u;
  __syncthreads();

  const float* xrow = x + (size_t)(bm + lm) * NT * ND + lkb;
  f32x4 xr[4];
#pragma unroll
  for (int xt = 0; xt < 2; ++xt) {
    xr[2 * xt]     = *(const f32x4*)(xrow + xt * 32);
    xr[2 * xt + 1] = *(const f32x4*)(xrow + xt * 32 + 4);
  }

  int cur = 0;
  for (int t = 0; t < NT; ++t) {
    const int nxt = cur ^ 1;

    // ---- x(t): fp32 -> fp16 hi/lo split ----
    half8 axh[2], axl[2];
#pragma unroll
    for (int xt = 0; xt < 2; ++xt) {
      float v[8];
      *(f32x4*)&v[0] = xr[2 * xt];
      *(f32x4*)&v[4] = xr[2 * xt + 1];
#pragma unroll
      for (int e = 0; e < 8; ++e) {
        _Float16 hi = (_Float16)v[e];
        axh[xt][e] = hi;
        axl[xt][e] = (_Float16)(v[e] - (float)hi);
      }
    }

    f32x4 acc[2];
    acc[0] = (f32x4){0.f, 0.f, 0.f, 0.f};
    acc[1] = (f32x4){0.f, 0.f, 0.f, 0.f};

    // ---- kt 0..7: B from LDS ----
#pragma unroll
    for (int kt = 0; kt < 8; ++kt) {
      half8 ah = *(const half8*)&hpeer[cur][0][lm][kt * 32 + lkb];
      half8 al = *(const half8*)&hpeer[cur][1][lm][kt * 32 + lkb];
#pragma unroll
      for (int nt = 0; nt < 2; ++nt) {
        half8 b = *(const half8*)&wlds[kt][w * 2 + nt][lane][0];
        acc[nt] = __builtin_amdgcn_mfma_f32_16x16x32_f16(ah, b, acc[nt], 0, 0, 0);
        acc[nt] = __builtin_amdgcn_mfma_f32_16x16x32_f16(al, b, acc[nt], 0, 0, 0);
      }
    }
    // ---- kt 8..15: B from VGPRs ----
#pragma unroll
    for (int q = 0; q < 8; ++q) {
      half8 ah = *(const half8*)&hpeer[cur][0][lm][(q + 8) * 32 + lkb];
      half8 al = *(const half8*)&hpeer[cur][1][lm][(q + 8) * 32 + lkb];
#pragma unroll
      for (int nt = 0; nt < 2; ++nt) {
        acc[nt] = __builtin_amdgcn_mfma_f32_16x16x32_f16(ah, wreg[q][nt], acc[nt], 0, 0, 0);
        acc[nt] = __builtin_amdgcn_mfma_f32_16x16x32_f16(al, wreg[q][nt], acc[nt], 0, 0, 0);
      }
    }
    // ---- x tiles ----
#pragma unroll
    for (int q = 0; q < 2; ++q)
#pragma unroll
      for (int nt = 0; nt < 2; ++nt) {
        acc[nt] = __builtin_amdgcn_mfma_f32_16x16x32_f16(axh[q], wx[q][nt], acc[nt], 0, 0, 0);
        acc[nt] = __builtin_amdgcn_mfma_f32_16x16x32_f16(axl[q], wx[q][nt], acc[nt], 0, 0, 0);
      }

    // ---- epilogue: tanh, fp16 split, tstage, out partials ----
    float po[4] = {0.f, 0.f, 0.f, 0.f};
#pragma unroll
    for (int nt = 0; nt < 2; ++nt) {
#pragma unroll
      for (int r = 0; r < 4; ++r) {
        float pre = acc[nt][r] + bv[nt];
        float hv  = tanh_fast(pre);
        const int m = lg * 4 + r;
        _Float16 hi = (_Float16)hv;
        tstage[w][0][m][nt * 16 + lm] = hi;
        tstage[w][1][m][nt * 16 + lm] = (_Float16)(hv - (float)hi);
        po[r] += hv * wov[nt];
      }
    }
#pragma unroll
    for (int s = 1; s < 16; s <<= 1)
#pragma unroll
      for (int r = 0; r < 4; ++r) po[r] += __shfl_xor(po[r], s, 64);
    if (lm == 0) {
#pragma unroll
      for (int r = 0; r < 4; ++r) posum[w][lg * 4 + r] = po[r];
    }

    // ---- publish own chunk (agent stores) + own-stage into hpeer[nxt] ----
    {
      const int prow = lane >> 2;
      const int pc8  = (lane & 3) * 8;
      const size_t pb = ((((size_t)((t + 1) & 1) * 16 + bg) * 16 + gko) * 2) * 512;
#pragma unroll
      for (int p = 0; p < 2; ++p) {
        H8 u;
        u.h = *(const half8*)&tstage[w][p][prow][pc8];
        ull* gd = (ull*)(hglob + pb + (size_t)p * 512 + prow * 32 + pc8);
        __hip_atomic_store(gd,     u.q[0], __ATOMIC_RELAXED, __HIP_MEMORY_SCOPE_AGENT);
        __hip_atomic_store(gd + 1, u.q[1], __ATOMIC_RELAXED, __HIP_MEMORY_SCOPE_AGENT);
        *(half8*)&hpeer[nxt][p][prow][n0 + pc8] = u.h;   // own cols, local
      }
    }
    asm volatile("s_waitcnt vmcnt(0)" ::: "memory");   // publish at coherence pt
    __syncthreads();   // B: all 4 chunks of this block published

    if (w == 0) {
      if (lane == 0)
        __hip_atomic_store(&flags[(bg * 4 + cb) * 32], (unsigned)(t + 1),
                           __ATOMIC_RELAXED, __HIP_MEMORY_SCOPE_AGENT);
      if (lane < 16) {
        float s = posum[0][lane] + posum[1][lane] + posum[2][lane] + posum[3][lane];
        partial[((size_t)cb * NB + bm + lane) * NT + t] = s;
      }
    }

    if (t + 1 < NT) {
      // x(t+1) prefetch (all waves)
#pragma unroll
      for (int xt = 0; xt < 2; ++xt) {
        xr[2 * xt]     = *(const f32x4*)(xrow + (size_t)(t + 1) * ND + xt * 32);
        xr[2 * xt + 1] = *(const f32x4*)(xrow + (size_t)(t + 1) * ND + xt * 32 + 4);
      }
      // waves 1..3: spin on ONE peer flag, fetch its 4 chunks, stage
      if (w > 0) {
        const int src = (cb + w) & 3;
        const unsigned int* fp = &flags[(bg * 4 + src) * 32];
        if (lane == 0) {
          while (__hip_atomic_load(fp, __ATOMIC_RELAXED, __HIP_MEMORY_SCOPE_AGENT)
                 < (unsigned)(t + 1))
            __builtin_amdgcn_s_sleep(1);
        }
        asm volatile("" ::: "memory");
        const int prow = lane >> 2;
        const int pc8  = (lane & 3) * 8;
        const size_t fb = (((size_t)((t + 1) & 1) * 16 + bg) * 16) * 2 * 512;
        H8 u[4][2];
#pragma unroll
        for (int c4 = 0; c4 < 4; ++c4) {
          const int gk = src * 4 + c4;
#pragma unroll
          for (int p = 0; p < 2; ++p) {
            const ull* gs = (const ull*)(hglob + fb + ((size_t)gk * 2 + p) * 512 +
                                         prow * 32 + pc8);
            u[c4][p].q[0] = __hip_atomic_load(gs,     __ATOMIC_RELAXED, __HIP_MEMORY_SCOPE_AGENT);
            u[c4][p].q[1] = __hip_atomic_load(gs + 1, __ATOMIC_RELAXED, __HIP_MEMORY_SCOPE_AGENT);
          }
        }
#pragma unroll
        for (int c4 = 0; c4 < 4; ++c4) {
          const int gk = src * 4 + c4;
#pragma unroll
          for (int p = 0; p < 2; ++p)
            *(half8*)&hpeer[nxt][p][prow][gk * 32 + pc8] = u[c4][p].h;
        }
      }
    }

    __syncthreads();   // C: hpeer[nxt] fully staged
    cur = nxt;
  }
}

extern "C" void kernel_launch(void* const* d_in, const int* in_sizes, int n_in,
                              void* d_out, int out_size, void* d_ws, size_t ws_size,
                              hipStream_t stream) {
  const float* x   = (const float*)d_in[0];
  const float* wih = (const float*)d_in[1];
  const float* whh = (const float*)d_in[2];
  const float* bih = (const float*)d_in[3];
  const float* bhh = (const float*)d_in[4];
  const float* who = (const float*)d_in[5];
  const float* bho = (const float*)d_in[6];
  float* out = (float*)d_out;

  // ws: wpk 576KB | hglob 1MB | flags 16KB | partial 2MB
  _Float16* wpk   = (_Float16*)d_ws;
  _Float16* hglob = wpk + (size_t)18 * 4 * 8 * 64 * 8;       // 294912 halves
  unsigned int* flags = (unsigned int*)(hglob + (size_t)2 * 16 * 16 * 2 * 512);
  float* partial = (float*)(flags + 4096);

  init_kernel<<<8, 256, 0, stream>>>(flags);
  prep_kernel<<<144, 256, 0, stream>>>(whh, wih, wpk);
  rnn_f16<<<64, 256, 0, stream>>>(x, wpk, bih, bhh, who, hglob, flags, partial);
  combine_kernel<<<512, 256, 0, stream>>>(partial, bho, out);
}